// Round 1
// baseline (3509.578 us; speedup 1.0000x reference)
//
#include <hip/hip_runtime.h>
#include <hip/hip_bf16.h>
#include <cmath>

// Problem constants
static constexpr int  Bn = 8;
static constexpr int  Nn = 1024;
static constexpr int  Dd = 256;
static constexpr int  NMASKED = 512;
static constexpr int  VOC = 32000;

// ---- workspace layout (float element offsets) ----
static constexpr long SZ_BND  = (long)Bn * Nn * Dd;       // 2,097,152
static constexpr long SZ_S    = (long)Bn * Nn * Nn;       // 8,388,608
static constexpr long OFF_X   = 0;
static constexpr long OFF_Q   = OFF_X  + SZ_BND;
static constexpr long OFF_K   = OFF_Q  + SZ_BND;
static constexpr long OFF_V   = OFF_K  + SZ_BND;
static constexpr long OFF_H   = OFF_V  + SZ_BND;
static constexpr long OFF_XM  = OFF_H  + SZ_BND;
static constexpr long OFF_S   = OFF_XM + SZ_BND;
static constexpr long OFF_PE  = OFF_S  + SZ_S;
static constexpr long OFF_PAD = OFF_PE + (long)Nn * Dd;
static constexpr long OFF_MSK = OFF_PAD + (long)Bn * Nn;
static constexpr long OFF_XR  = OFF_MSK + (long)Bn * Nn;

// ---------------- setup kernels ----------------

__global__ __launch_bounds__(256) void k_pe(float* __restrict__ PE) {
    int g = blockIdx.x * 256 + threadIdx.x;        // Nn * Dd/2 threads
    int p = g >> 7;                                 // position
    int j = g & 127;                                // half-dim index
    float di   = (float)j * (1.0f / 128.0f);
    float freq = powf(10000.0f, -di);
    float ang  = (float)p * freq;
    PE[(long)p * Dd + j]       = sinf(ang);
    PE[(long)p * Dd + j + 128] = cosf(ang);
}

__global__ __launch_bounds__(256) void k_flags(const int* __restrict__ ix,
                                               int* __restrict__ padf,
                                               int* __restrict__ maskf) {
    int g = blockIdx.x * 256 + threadIdx.x;
    if (g < Bn * Nn) {
        int t = ix[g];
        padf[g]  = (t == 0) ? 1 : 0;
        maskf[g] = (t == 1) ? 1 : 0;
    }
}

__global__ __launch_bounds__(256) void k_embed(const int* __restrict__ ix,
                                               const float* __restrict__ emb,
                                               float* __restrict__ X) {
    int g = blockIdx.x * 256 + threadIdx.x;   // (Bn*Nn*Dd)/4 threads
    long e = (long)g * 4;
    int bn = (int)(e >> 8);
    int k  = (int)(e & 255);
    int tok = ix[bn];
    float4 v;
    if (tok == 1) v = make_float4(0.f, 0.f, 0.f, 0.f);
    else          v = *(const float4*)(emb + (long)tok * Dd + k);
    *(float4*)(X + e) = v;
}

// ---------------- generic tiled GEMM ----------------
// C[M,N] (+)= opA(A) @ opB(B); TA: A stored [K,M] (lda=M); TB: B stored [N,K] (ldb=K).
// ADDPE: A element (i,k) += PE[i & 1023][k]  (only valid with !TA, lda == Dd).
template<bool TA, bool TB, bool ADDPE, bool ACCUM>
__global__ __launch_bounds__(256)
void k_gemm(const float* __restrict__ A, const float* __restrict__ B,
            float* __restrict__ C, const float* __restrict__ PE,
            int K, int lda, int ldb, int ldc,
            long sA, long sB, long sC) {
    const int bz = blockIdx.z;
    A += (long)bz * sA;  B += (long)bz * sB;  C += (long)bz * sC;
    const int i0 = blockIdx.x * 64;
    const int j0 = blockIdx.y * 64;

    __shared__ float As[16][68];
    __shared__ float Bs[16][68];

    const int t  = threadIdx.x;
    const int ty = t >> 4;        // 0..15 (row group)
    const int tx = t & 15;        // 0..15 (col group)

    float acc[4][4] = {{0.f}};

    for (int k0 = 0; k0 < K; k0 += 16) {
        if (!TA) {
            int ii = t >> 2, kq = (t & 3) << 2;
            float4 v = *(const float4*)(A + (long)(i0 + ii) * lda + (k0 + kq));
            if (ADDPE) {
                float4 pe = *(const float4*)(PE + (long)((i0 + ii) & 1023) * Dd + (k0 + kq));
                v.x += pe.x; v.y += pe.y; v.z += pe.z; v.w += pe.w;
            }
            As[kq + 0][ii] = v.x; As[kq + 1][ii] = v.y;
            As[kq + 2][ii] = v.z; As[kq + 3][ii] = v.w;
        } else {
            int kk = t >> 4, iq = (t & 15) << 2;
            *(float4*)&As[kk][iq] = *(const float4*)(A + (long)(k0 + kk) * lda + (i0 + iq));
        }
        if (TB) {
            int jj = t >> 2, kq = (t & 3) << 2;
            float4 v = *(const float4*)(B + (long)(j0 + jj) * ldb + (k0 + kq));
            Bs[kq + 0][jj] = v.x; Bs[kq + 1][jj] = v.y;
            Bs[kq + 2][jj] = v.z; Bs[kq + 3][jj] = v.w;
        } else {
            int kk = t >> 4, jq = (t & 15) << 2;
            *(float4*)&Bs[kk][jq] = *(const float4*)(B + (long)(k0 + kk) * ldb + (j0 + jq));
        }
        __syncthreads();
#pragma unroll
        for (int kk = 0; kk < 16; ++kk) {
            float4 a  = *(const float4*)&As[kk][ty << 2];
            float4 bv = *(const float4*)&Bs[kk][tx << 2];
            acc[0][0] += a.x * bv.x; acc[0][1] += a.x * bv.y; acc[0][2] += a.x * bv.z; acc[0][3] += a.x * bv.w;
            acc[1][0] += a.y * bv.x; acc[1][1] += a.y * bv.y; acc[1][2] += a.y * bv.z; acc[1][3] += a.y * bv.w;
            acc[2][0] += a.z * bv.x; acc[2][1] += a.z * bv.y; acc[2][2] += a.z * bv.z; acc[2][3] += a.z * bv.w;
            acc[3][0] += a.w * bv.x; acc[3][1] += a.w * bv.y; acc[3][2] += a.w * bv.z; acc[3][3] += a.w * bv.w;
        }
        __syncthreads();
    }

#pragma unroll
    for (int r = 0; r < 4; ++r) {
        float* cp = C + (long)(i0 + (ty << 2) + r) * ldc + j0 + (tx << 2);
        float4 o;
        if (ACCUM) {
            float4 old = *(const float4*)cp;
            o = make_float4(old.x + acc[r][0], old.y + acc[r][1],
                            old.z + acc[r][2], old.w + acc[r][3]);
        } else {
            o = make_float4(acc[r][0], acc[r][1], acc[r][2], acc[r][3]);
        }
        *(float4*)cp = o;
    }
}

// ---------------- fused mask/scale/softmax over S rows ----------------
__global__ __launch_bounds__(256) void k_softmax(float* __restrict__ S,
                                                 const int* __restrict__ padf) {
    const int i = blockIdx.x;
    const int b = blockIdx.y;
    const int t = threadIdx.x;
    float* row = S + ((long)(b * Nn + i)) * Nn;
    const int* pr = padf + b * Nn;
    const int padi = pr[i];

    float4 v = *(const float4*)(row + t * 4);
    float x[4]; int pm[4];
#pragma unroll
    for (int q = 0; q < 4; ++q) {
        int j = t * 4 + q;
        pm[q] = padi | pr[j];
        float raw = (&v.x)[q];
        x[q] = (raw + (pm[q] ? -9999.0f : 0.0f)) * 0.0625f;
    }
    float m = fmaxf(fmaxf(x[0], x[1]), fmaxf(x[2], x[3]));
#pragma unroll
    for (int o = 32; o > 0; o >>= 1) m = fmaxf(m, __shfl_down(m, o));
    __shared__ float r1[4], r2[4];
    const int lane = t & 63, wid = t >> 6;
    if (lane == 0) r1[wid] = m;
    __syncthreads();
    m = fmaxf(fmaxf(r1[0], r1[1]), fmaxf(r1[2], r1[3]));

    float e[4]; float s = 0.f;
#pragma unroll
    for (int q = 0; q < 4; ++q) { e[q] = expf(x[q] - m); s += e[q]; }
#pragma unroll
    for (int o = 32; o > 0; o >>= 1) s += __shfl_down(s, o);
    if (lane == 0) r2[wid] = s;
    __syncthreads();
    s = r2[0] + r2[1] + r2[2] + r2[3];
    const float inv = 1.0f / s;
#pragma unroll
    for (int q = 0; q < 4; ++q) (&v.x)[q] = pm[q] ? 0.0f : e[q] * inv;
    *(float4*)(row + t * 4) = v;
}

// ---------------- X = where(mask, Xm, X) ----------------
__global__ __launch_bounds__(256) void k_xupd(float* __restrict__ X,
                                              const float* __restrict__ Xm,
                                              const int* __restrict__ maskf) {
    int g = blockIdx.x * 256 + threadIdx.x;
    long e = (long)g * 4;
    int bn = (int)(e >> 8);
    if (maskf[bn]) *(float4*)(X + e) = *(const float4*)(Xm + e);
}

// ---------------- gather masked rows of Xm ----------------
__global__ __launch_bounds__(64) void k_gather(const float* __restrict__ Xm,
                                               const int* __restrict__ midx,
                                               float* __restrict__ R) {
    int r = blockIdx.x;
    int t = threadIdx.x;
    long src = (long)midx[r] * Dd + t * 4;
    *(float4*)(R + (long)r * Dd + t * 4) = *(const float4*)(Xm + src);
}

// ---------------- launcher ----------------
extern "C" void kernel_launch(void* const* d_in, const int* in_sizes, int n_in,
                              void* d_out, int out_size, void* d_ws, size_t ws_size,
                              hipStream_t stream) {
    (void)in_sizes; (void)n_in; (void)out_size; (void)ws_size;
    const int*   ix   = (const int*)d_in[0];
    const int*   midx = (const int*)d_in[1];
    const float* emb  = (const float*)d_in[2];
    const float* Wq   = (const float*)d_in[3];
    const float* Wk   = (const float*)d_in[4];
    const float* Wv   = (const float*)d_in[5];

    float* ws  = (float*)d_ws;
    float* X   = ws + OFF_X;
    float* Q   = ws + OFF_Q;
    float* Kb  = ws + OFF_K;
    float* V   = ws + OFF_V;
    float* H   = ws + OFF_H;
    float* Xm  = ws + OFF_XM;
    float* S   = ws + OFF_S;
    float* PE  = ws + OFF_PE;
    int*   padf  = (int*)(ws + OFF_PAD);
    int*   maskf = (int*)(ws + OFF_MSK);
    float* XR  = ws + OFF_XR;
    float* out = (float*)d_out;

    // zero-init persistent state (S, K, H start as zeros each call)
    hipMemsetAsync(S,  0, SZ_S   * sizeof(float), stream);
    hipMemsetAsync(Kb, 0, SZ_BND * sizeof(float), stream);
    hipMemsetAsync(H,  0, SZ_BND * sizeof(float), stream);

    k_pe   <<<dim3((Nn * Dd / 2) / 256), 256, 0, stream>>>(PE);
    k_flags<<<dim3((Bn * Nn) / 256),     256, 0, stream>>>(ix, padf, maskf);
    k_embed<<<dim3((int)(SZ_BND / 4 / 256)), 256, 0, stream>>>(ix, emb, X);

    const dim3 gW(Bn * Nn / 64, Dd / 64, 1);   // (128,4,1): [8192,256] x [256,256]
    const dim3 gS(Nn / 64, Dd / 64, Bn);       // (16,4,8):  [1024,1024] x [1024,256]
    const dim3 gSc(Nn / 64, Nn / 64, Bn);      // (16,16,8): [1024,256] x [256,1024]
    const long sS = (long)Nn * Nn, sD = (long)Nn * Dd;

    for (int it = 0; it < 3; ++it) {
        // Q = Xp @ Wq^T + S @ K
        k_gemm<false,true ,true ,false><<<gW, 256, 0, stream>>>(X,  Wq, Q,  PE, Dd, Dd, Dd, Dd, 0, 0, 0);
        k_gemm<false,false,false,true ><<<gS, 256, 0, stream>>>(S,  Kb, Q,  PE, Nn, Nn, Dd, Dd, sS, sD, sD);
        // K = Xp @ Wk^T + S^T @ Q
        k_gemm<false,true ,true ,false><<<gW, 256, 0, stream>>>(X,  Wk, Kb, PE, Dd, Dd, Dd, Dd, 0, 0, 0);
        k_gemm<true ,false,false,true ><<<gS, 256, 0, stream>>>(S,  Q,  Kb, PE, Nn, Nn, Dd, Dd, sS, sD, sD);
        // V = Xp @ Wv^T + S^T @ H
        k_gemm<false,true ,true ,false><<<gW, 256, 0, stream>>>(X,  Wv, V,  PE, Dd, Dd, Dd, Dd, 0, 0, 0);
        k_gemm<true ,false,false,true ><<<gS, 256, 0, stream>>>(S,  H,  V,  PE, Nn, Nn, Dd, Dd, sS, sD, sD);
        // S = softmax((Q K^T + H V^T + mask)/16), pad-zeroed
        k_gemm<false,true ,false,false><<<gSc,256, 0, stream>>>(Q,  Kb, S,  PE, Dd, Dd, Dd, Nn, sD, sD, sS);
        k_gemm<false,true ,false,true ><<<gSc,256, 0, stream>>>(H,  V,  S,  PE, Dd, Dd, Dd, Nn, sD, sD, sS);
        k_softmax<<<dim3(Nn, Bn, 1), 256, 0, stream>>>(S, padf);
        // H = S @ V
        k_gemm<false,false,false,false><<<gS, 256, 0, stream>>>(S,  V,  H,  PE, Nn, Nn, Dd, Dd, sS, sD, sD);
        // S = update again (new H)
        k_gemm<false,true ,false,false><<<gSc,256, 0, stream>>>(Q,  Kb, S,  PE, Dd, Dd, Dd, Nn, sD, sD, sS);
        k_gemm<false,true ,false,true ><<<gSc,256, 0, stream>>>(H,  V,  S,  PE, Dd, Dd, Dd, Nn, sD, sD, sS);
        k_softmax<<<dim3(Nn, Bn, 1), 256, 0, stream>>>(S, padf);
        // V = Xp @ Wv^T + S^T @ H
        k_gemm<false,true ,true ,false><<<gW, 256, 0, stream>>>(X,  Wv, V,  PE, Dd, Dd, Dd, Dd, 0, 0, 0);
        k_gemm<true ,false,false,true ><<<gS, 256, 0, stream>>>(S,  H,  V,  PE, Nn, Nn, Dd, Dd, sS, sD, sD);
        // K = Xp @ Wk^T + S^T @ Q
        k_gemm<false,true ,true ,false><<<gW, 256, 0, stream>>>(X,  Wk, Kb, PE, Dd, Dd, Dd, Dd, 0, 0, 0);
        k_gemm<true ,false,false,true ><<<gS, 256, 0, stream>>>(S,  Q,  Kb, PE, Nn, Nn, Dd, Dd, sS, sD, sD);
        // Q = Xp @ Wq^T + S @ K
        k_gemm<false,true ,true ,false><<<gW, 256, 0, stream>>>(X,  Wq, Q,  PE, Dd, Dd, Dd, Dd, 0, 0, 0);
        k_gemm<false,false,false,true ><<<gS, 256, 0, stream>>>(S,  Kb, Q,  PE, Nn, Nn, Dd, Dd, sS, sD, sD);
        // Xm = V @ Wv + K @ Wk + Q @ Wq   (no transpose)
        k_gemm<false,false,false,false><<<gW, 256, 0, stream>>>(V,  Wv, Xm, PE, Dd, Dd, Dd, Dd, 0, 0, 0);
        k_gemm<false,false,false,true ><<<gW, 256, 0, stream>>>(Kb, Wk, Xm, PE, Dd, Dd, Dd, Dd, 0, 0, 0);
        k_gemm<false,false,false,true ><<<gW, 256, 0, stream>>>(Q,  Wq, Xm, PE, Dd, Dd, Dd, Dd, 0, 0, 0);
        // X = where(mask, Xm, X)
        k_xupd<<<dim3((int)(SZ_BND / 4 / 256)), 256, 0, stream>>>(X, Xm, maskf);
    }
    // logits = Xm_rows @ emb^T
    k_gather<<<dim3(NMASKED), 64, 0, stream>>>(Xm, midx, XR);
    k_gemm<false,true ,false,false><<<dim3(NMASKED / 64, VOC / 64, 1), 256, 0, stream>>>(
        XR, emb, out, PE, Dd, Dd, Dd, VOC, 0, 0, 0);
}

// Round 2
// 1439.607 us; speedup vs baseline: 2.4379x; 2.4379x over previous
//
#include <hip/hip_runtime.h>
#include <hip/hip_bf16.h>

typedef __attribute__((ext_vector_type(8))) short bf16x8;
typedef __attribute__((ext_vector_type(4))) float f32x4;
typedef unsigned short u16;

// ---------------- bf16 helpers (RNE) ----------------
static __device__ __forceinline__ float bf2f(u16 u) {
    union { unsigned int i; float f; } c; c.i = ((unsigned int)u) << 16; return c.f;
}
static __device__ __forceinline__ u16 f2bf(float f) {
    union { float f; unsigned int i; } c; c.f = f;
    unsigned int r = c.i + 0x7fffu + ((c.i >> 16) & 1u);
    return (u16)(r >> 16);
}

#define AS1(p) ((const __attribute__((address_space(1))) void*)(p))
#define AS3(p) ((__attribute__((address_space(3))) void*)(p))
static __device__ __forceinline__ void glds16(const void* g, void* l) {
    __builtin_amdgcn_global_load_lds(AS1(g), AS3(l), 16, 0, 0);
}

// ---------------- workspace layout (byte offsets) ----------------
static constexpr long B_X   = 0;                        // fp32 X      [8,1024,256]
static constexpr long B_Q   = B_X   + 8388608;          // fp32 Q      (also score buf part)
static constexpr long B_K   = B_Q   + 8388608;          // fp32 K
static constexpr long B_V   = B_K   + 8388608;          // fp32 V
static constexpr long B_H   = B_V   + 8388608;          // fp32 H
static constexpr long B_XM  = B_H   + 8388608;          // fp32 Xm
static constexpr long B_PE  = B_XM  + 8388608;          // fp32 PE     [1024,256]
static constexpr long B_PAD = B_PE  + 1048576;          // int pad flags
static constexpr long B_MSK = B_PAD + 32768;            // int mask flags
static constexpr long B_XPB = B_MSK + 32768;            // bf16 Xp     [8192,256]
static constexpr long B_QH  = B_XPB + 4194304;          // bf16 [Q|H]  [8,1024,512]
static constexpr long B_KV  = B_QH  + 8388608;          // bf16 [K|V]  [8,1024,512]
static constexpr long B_QT  = B_KV  + 8388608;          // bf16 Q^T    [8,256,1024]
static constexpr long B_KT  = B_QT  + 4194304;          // bf16 K^T
static constexpr long B_VT  = B_KT  + 4194304;          // bf16 V^T
static constexpr long B_HT  = B_VT  + 4194304;          // bf16 H^T
static constexpr long B_SB  = B_HT  + 4194304;          // bf16 S      [8,1024,1024]
static constexpr long B_STB = B_SB  + 16777216;         // bf16 S^T
static constexpr long B_EMB = B_STB + 16777216;         // bf16 emb    [32000,256]
static constexpr long B_WQ  = B_EMB + 16384000;         // bf16 Wq     [256,256]
static constexpr long B_WQT = B_WQ  + 131072;
static constexpr long B_WK  = B_WQT + 131072;
static constexpr long B_WKT = B_WK  + 131072;
static constexpr long B_WV  = B_WKT + 131072;
static constexpr long B_WVT = B_WV  + 131072;
static constexpr long B_XRB = B_WVT + 131072;           // bf16 gathered rows [512,256]
// end ~140.2 MB.  NOTE: fp32 score buffer Sf aliases [B_Q, B_XM) == Q,K,V,H (dead there).

// ---------------- setup kernels ----------------
__global__ __launch_bounds__(256) void k_pe(float* __restrict__ PE) {
    int g = blockIdx.x * 256 + threadIdx.x;
    int p = g >> 7, j = g & 127;
    float di   = (float)j * (1.0f / 128.0f);
    float freq = powf(10000.0f, -di);
    float ang  = (float)p * freq;
    PE[(long)p * 256 + j]       = sinf(ang);
    PE[(long)p * 256 + j + 128] = cosf(ang);
}

__global__ __launch_bounds__(256) void k_flags(const int* __restrict__ ix,
                                               int* __restrict__ padf, int* __restrict__ maskf) {
    int g = blockIdx.x * 256 + threadIdx.x;
    int t = ix[g];
    padf[g]  = (t == 0) ? 1 : 0;
    maskf[g] = (t == 1) ? 1 : 0;
}

__global__ __launch_bounds__(256) void k_embed(const int* __restrict__ ix,
                                               const float* __restrict__ emb, float* __restrict__ X) {
    int g = blockIdx.x * 256 + threadIdx.x;
    long e = (long)g * 4;
    int bn = (int)(e >> 8), k = (int)(e & 255);
    int tok = ix[bn];
    float4 v;
    if (tok == 1) v = make_float4(0.f, 0.f, 0.f, 0.f);
    else          v = *(const float4*)(emb + (long)tok * 256 + k);
    *(float4*)(X + e) = v;
}

// Xp = bf16(X + PE)
__global__ __launch_bounds__(256) void k_xpe(const float* __restrict__ X,
                                             const float* __restrict__ PE, u16* __restrict__ out) {
    int g = blockIdx.x * 256 + threadIdx.x;
    long e = (long)g * 4;
    int i = (int)((e >> 8) & 1023), c = (int)(e & 255);
    float4 x = *(const float4*)(X + e);
    float4 p = *(const float4*)(PE + (long)i * 256 + c);
    ushort4 o;
    o.x = f2bf(x.x + p.x); o.y = f2bf(x.y + p.y);
    o.z = f2bf(x.z + p.z); o.w = f2bf(x.w + p.w);
    *(ushort4*)(out + e) = o;
}

// ---------------- fp32 -> bf16 convert (+ optional per-batch transpose), src ld fixed 256 ----------------
__global__ __launch_bounds__(256)
void k_cvt(const float* __restrict__ src, long srcStride,
           u16* __restrict__ dst, int dld, long dStride,
           u16* __restrict__ dstT, int tld, long tStride) {
    __shared__ u16 tile[32][33];
    const int bx = blockIdx.x, by = blockIdx.y, bz = blockIdx.z;
    const int tx = threadIdx.x & 31, ty = threadIdx.x >> 5;
    const float* s = src + (long)bz * srcStride;
#pragma unroll
    for (int r = 0; r < 32; r += 8) {
        float v = s[(long)(bx * 32 + ty + r) * 256 + by * 32 + tx];
        u16 u = f2bf(v);
        dst[(long)bz * dStride + (long)(bx * 32 + ty + r) * dld + by * 32 + tx] = u;
        tile[ty + r][tx] = u;
    }
    if (dstT) {
        __syncthreads();
#pragma unroll
        for (int r = 0; r < 32; r += 8)
            dstT[(long)bz * tStride + (long)(by * 32 + ty + r) * tld + bx * 32 + tx] = tile[tx][ty + r];
    }
}

// bf16 [1024,1024] batched transpose
__global__ __launch_bounds__(256)
void k_tr(const u16* __restrict__ src, u16* __restrict__ dst) {
    __shared__ u16 tile[32][33];
    const int bx = blockIdx.x, by = blockIdx.y;
    const long base = (long)blockIdx.z << 20;
    const int tx = threadIdx.x & 31, ty = threadIdx.x >> 5;
#pragma unroll
    for (int r = 0; r < 32; r += 8)
        tile[ty + r][tx] = src[base + (long)(bx * 32 + ty + r) * 1024 + by * 32 + tx];
    __syncthreads();
#pragma unroll
    for (int r = 0; r < 32; r += 8)
        dst[base + (long)(by * 32 + ty + r) * 1024 + bx * 32 + tx] = tile[tx][ty + r];
}

// ---------------- MFMA GEMM: C[M,N] (+)= A @ B^T ; A [M,K] row-major, B [N,K] row-major, bf16 ----------------
template<bool ACCUM>
__global__ __launch_bounds__(256)
void k_mf(const u16* __restrict__ A, const u16* __restrict__ B, float* __restrict__ C,
          int K, int lda, int ldb, int ldc, long sA, long sB, long sC) {
    A += (long)blockIdx.z * sA;
    B += (long)blockIdx.z * sB;
    C += (long)blockIdx.z * sC;
    const int i0 = blockIdx.x * 128, j0 = blockIdx.y * 128;
    __shared__ u16 As[128 * 32];
    __shared__ u16 Bs[128 * 32];
    const int t = threadIdx.x;
    const int w = t >> 6, l = t & 63;
    const int wr = (w >> 1) << 6, wc = (w & 1) << 6;
    const int lr = l & 15, lk = (l >> 4) << 3;

    f32x4 acc[4][4] = {};

    const u16* ga = A + (long)(i0 + (t >> 2)) * lda + ((t & 3) << 3);
    const u16* gb = B + (long)(j0 + (t >> 2)) * ldb + ((t & 3) << 3);
    const long a64 = (long)lda << 6, b64 = (long)ldb << 6;
    char* lA = (char*)As + (w << 10);
    char* lB = (char*)Bs + (w << 10);

    for (int k0 = 0; k0 < K; k0 += 32) {
        glds16(ga + k0,       lA);
        glds16(ga + k0 + a64, lA + 4096);
        glds16(gb + k0,       lB);
        glds16(gb + k0 + b64, lB + 4096);
        __syncthreads();
        bf16x8 af[4], bfr[4];
#pragma unroll
        for (int m = 0; m < 4; ++m)
            af[m] = *(const bf16x8*)(As + ((wr + (m << 4) + lr) << 5) + lk);
#pragma unroll
        for (int n = 0; n < 4; ++n)
            bfr[n] = *(const bf16x8*)(Bs + ((wc + (n << 4) + lr) << 5) + lk);
#pragma unroll
        for (int m = 0; m < 4; ++m)
#pragma unroll
            for (int n = 0; n < 4; ++n)
                acc[m][n] = __builtin_amdgcn_mfma_f32_16x16x32_bf16(af[m], bfr[n], acc[m][n], 0, 0, 0);
        __syncthreads();
    }

    const int rb = i0 + wr + ((l >> 4) << 2);
    const int cb = j0 + wc + lr;
#pragma unroll
    for (int m = 0; m < 4; ++m)
#pragma unroll
        for (int n = 0; n < 4; ++n)
#pragma unroll
            for (int j = 0; j < 4; ++j) {
                long off = (long)(rb + (m << 4) + j) * ldc + cb + (n << 4);
                if (ACCUM) C[off] += acc[m][n][j];
                else       C[off]  = acc[m][n][j];
            }
}

// ---------------- softmax: fp32 scores -> bf16 S (mask, /16, softmax, pad-zero) ----------------
__global__ __launch_bounds__(256)
void k_softmax(const float* __restrict__ Sf, u16* __restrict__ Sb, const int* __restrict__ padf) {
    const int i = blockIdx.x, b = blockIdx.y, t = threadIdx.x;
    const float* row = Sf + ((long)(b * 1024 + i)) * 1024;
    u16* orow = Sb + ((long)(b * 1024 + i)) * 1024;
    const int* pr = padf + b * 1024;
    const int padi = pr[i];

    float4 v = *(const float4*)(row + t * 4);
    float x[4]; int pm[4];
#pragma unroll
    for (int q = 0; q < 4; ++q) {
        int j = t * 4 + q;
        pm[q] = padi | pr[j];
        x[q] = ((&v.x)[q] + (pm[q] ? -9999.0f : 0.0f)) * 0.0625f;
    }
    float m = fmaxf(fmaxf(x[0], x[1]), fmaxf(x[2], x[3]));
#pragma unroll
    for (int o = 32; o > 0; o >>= 1) m = fmaxf(m, __shfl_down(m, o));
    __shared__ float r1[4], r2[4];
    const int lane = t & 63, wid = t >> 6;
    if (lane == 0) r1[wid] = m;
    __syncthreads();
    m = fmaxf(fmaxf(r1[0], r1[1]), fmaxf(r1[2], r1[3]));
    float e[4]; float s = 0.f;
#pragma unroll
    for (int q = 0; q < 4; ++q) { e[q] = expf(x[q] - m); s += e[q]; }
#pragma unroll
    for (int o = 32; o > 0; o >>= 1) s += __shfl_down(s, o);
    if (lane == 0) r2[wid] = s;
    __syncthreads();
    s = r2[0] + r2[1] + r2[2] + r2[3];
    const float inv = 1.0f / s;
    ushort4 o4;
    o4.x = pm[0] ? (u16)0 : f2bf(e[0] * inv);
    o4.y = pm[1] ? (u16)0 : f2bf(e[1] * inv);
    o4.z = pm[2] ? (u16)0 : f2bf(e[2] * inv);
    o4.w = pm[3] ? (u16)0 : f2bf(e[3] * inv);
    *(ushort4*)(orow + t * 4) = o4;
}

// ---------------- X = where(mask, Xm, X) ----------------
__global__ __launch_bounds__(256) void k_xupd(float* __restrict__ X, const float* __restrict__ Xm,
                                              const int* __restrict__ maskf) {
    int g = blockIdx.x * 256 + threadIdx.x;
    long e = (long)g * 4;
    int bn = (int)(e >> 8);
    if (maskf[bn]) *(float4*)(X + e) = *(const float4*)(Xm + e);
}

// ---------------- gather masked Xm rows -> bf16 ----------------
__global__ __launch_bounds__(256) void k_gatherb(const float* __restrict__ Xm,
                                                 const int* __restrict__ midx, u16* __restrict__ R) {
    int r = blockIdx.x, t = threadIdx.x;
    R[(long)r * 256 + t] = f2bf(Xm[(long)midx[r] * 256 + t]);
}

// ---------------- launcher ----------------
extern "C" void kernel_launch(void* const* d_in, const int* in_sizes, int n_in,
                              void* d_out, int out_size, void* d_ws, size_t ws_size,
                              hipStream_t stream) {
    (void)in_sizes; (void)n_in; (void)out_size; (void)ws_size;
    const int*   ix   = (const int*)d_in[0];
    const int*   midx = (const int*)d_in[1];
    const float* emb  = (const float*)d_in[2];
    const float* Wq   = (const float*)d_in[3];
    const float* Wk   = (const float*)d_in[4];
    const float* Wv   = (const float*)d_in[5];

    char* base = (char*)d_ws;
    float* Xf  = (float*)(base + B_X);
    float* Qf  = (float*)(base + B_Q);
    float* Kf  = (float*)(base + B_K);
    float* Vf  = (float*)(base + B_V);
    float* Hf  = (float*)(base + B_H);
    float* Xmf = (float*)(base + B_XM);
    float* Sf  = (float*)(base + B_Q);    // fp32 scores alias Q..H (dead during score windows)
    float* PEf = (float*)(base + B_PE);
    int*   padf  = (int*)(base + B_PAD);
    int*   maskf = (int*)(base + B_MSK);
    u16* Xpb  = (u16*)(base + B_XPB);
    u16* QHb  = (u16*)(base + B_QH);
    u16* KVb  = (u16*)(base + B_KV);
    u16* QT   = (u16*)(base + B_QT);
    u16* KT   = (u16*)(base + B_KT);
    u16* VT   = (u16*)(base + B_VT);
    u16* HT   = (u16*)(base + B_HT);
    u16* Sb   = (u16*)(base + B_SB);
    u16* STb  = (u16*)(base + B_STB);
    u16* embB = (u16*)(base + B_EMB);
    u16* Wqb  = (u16*)(base + B_WQ);
    u16* WqTb = (u16*)(base + B_WQT);
    u16* Wkb  = (u16*)(base + B_WK);
    u16* WkTb = (u16*)(base + B_WKT);
    u16* Wvb  = (u16*)(base + B_WV);
    u16* WvTb = (u16*)(base + B_WVT);
    u16* XRb  = (u16*)(base + B_XRB);
    float* out = (float*)d_out;

    // S, S^T, K^T, H^T, and QH (for H slot) start at zero
    hipMemsetAsync(Sb,  0, 16777216, stream);
    hipMemsetAsync(STb, 0, 16777216, stream);
    hipMemsetAsync(KT,  0, 4194304,  stream);
    hipMemsetAsync(HT,  0, 4194304,  stream);
    hipMemsetAsync(QHb, 0, 8388608,  stream);

    k_pe   <<<512,  256, 0, stream>>>(PEf);
    k_flags<<<32,   256, 0, stream>>>(ix, padf, maskf);
    k_embed<<<2048, 256, 0, stream>>>(ix, emb, Xf);
    // weights -> bf16 (normal + transposed); emb -> bf16
    k_cvt<<<dim3(8, 8, 1), 256, 0, stream>>>(Wq, 0, Wqb, 256, 0, WqTb, 256, 0);
    k_cvt<<<dim3(8, 8, 1), 256, 0, stream>>>(Wk, 0, Wkb, 256, 0, WkTb, 256, 0);
    k_cvt<<<dim3(8, 8, 1), 256, 0, stream>>>(Wv, 0, Wvb, 256, 0, WvTb, 256, 0);
    k_cvt<<<dim3(1000, 8, 1), 256, 0, stream>>>(emb, 0, embB, 256, 0, nullptr, 0, 0);

    const dim3 gw(64, 2, 1);      // [8192,256] x [256,*]
    const dim3 gs(8, 2, 8);       // [1024,256] batched, K=1024
    const dim3 gsc(8, 8, 8);      // scores [1024,1024], K=512
    const dim3 gcv(32, 8, 8);     // cvt QKVH
    const long sS2 = 1024L * 1024, sTD = 256L * 1024, sDD = 1024L * 256, sQH = 1024L * 512;

    for (int it = 0; it < 3; ++it) {
        k_xpe<<<2048, 256, 0, stream>>>(Xf, PEf, Xpb);
        // Q = Xp Wq^T + S K
        k_mf<false><<<gw, 256, 0, stream>>>(Xpb, Wqb, Qf, 256, 256, 256, 256, 0, 0, 0);
        k_mf<true ><<<gs, 256, 0, stream>>>(Sb, KT, Qf, 1024, 1024, 1024, 256, sS2, sTD, sDD);
        k_cvt<<<gcv, 256, 0, stream>>>(Qf, sDD, QHb + 0, 512, sQH, QT, 1024, sTD);
        // K = Xp Wk^T + S^T Q
        k_mf<false><<<gw, 256, 0, stream>>>(Xpb, Wkb, Kf, 256, 256, 256, 256, 0, 0, 0);
        k_mf<true ><<<gs, 256, 0, stream>>>(STb, QT, Kf, 1024, 1024, 1024, 256, sS2, sTD, sDD);
        k_cvt<<<gcv, 256, 0, stream>>>(Kf, sDD, KVb + 0, 512, sQH, nullptr, 0, 0);
        // V = Xp Wv^T + S^T H
        k_mf<false><<<gw, 256, 0, stream>>>(Xpb, Wvb, Vf, 256, 256, 256, 256, 0, 0, 0);
        k_mf<true ><<<gs, 256, 0, stream>>>(STb, HT, Vf, 1024, 1024, 1024, 256, sS2, sTD, sDD);
        k_cvt<<<gcv, 256, 0, stream>>>(Vf, sDD, KVb + 256, 512, sQH, VT, 1024, sTD);
        // scores = QK^T + HV^T (single K=512 GEMM, fp32 out into aliased Sf)
        k_mf<false><<<gsc, 256, 0, stream>>>(QHb, KVb, Sf, 512, 512, 512, 1024, sQH, sQH, sS2);
        k_softmax<<<dim3(1024, 8), 256, 0, stream>>>(Sf, Sb, padf);
        k_tr<<<dim3(32, 32, 8), 256, 0, stream>>>(Sb, STb);
        // H = S V
        k_mf<false><<<gs, 256, 0, stream>>>(Sb, VT, Hf, 1024, 1024, 1024, 256, sS2, sTD, sDD);
        k_cvt<<<gcv, 256, 0, stream>>>(Hf, sDD, QHb + 256, 512, sQH, HT, 1024, sTD);
        // scores again (new H)
        k_mf<false><<<gsc, 256, 0, stream>>>(QHb, KVb, Sf, 512, 512, 512, 1024, sQH, sQH, sS2);
        k_softmax<<<dim3(1024, 8), 256, 0, stream>>>(Sf, Sb, padf);
        k_tr<<<dim3(32, 32, 8), 256, 0, stream>>>(Sb, STb);
        // V = Xp Wv^T + S^T H
        k_mf<false><<<gw, 256, 0, stream>>>(Xpb, Wvb, Vf, 256, 256, 256, 256, 0, 0, 0);
        k_mf<true ><<<gs, 256, 0, stream>>>(STb, HT, Vf, 1024, 1024, 1024, 256, sS2, sTD, sDD);
        k_cvt<<<gcv, 256, 0, stream>>>(Vf, sDD, KVb + 256, 512, sQH, nullptr, 0, 0);
        // K = Xp Wk^T + S^T Q
        k_mf<false><<<gw, 256, 0, stream>>>(Xpb, Wkb, Kf, 256, 256, 256, 256, 0, 0, 0);
        k_mf<true ><<<gs, 256, 0, stream>>>(STb, QT, Kf, 1024, 1024, 1024, 256, sS2, sTD, sDD);
        k_cvt<<<gcv, 256, 0, stream>>>(Kf, sDD, KVb + 0, 512, sQH, KT, 1024, sTD);
        // Q = Xp Wq^T + S K
        k_mf<false><<<gw, 256, 0, stream>>>(Xpb, Wqb, Qf, 256, 256, 256, 256, 0, 0, 0);
        k_mf<true ><<<gs, 256, 0, stream>>>(Sb, KT, Qf, 1024, 1024, 1024, 256, sS2, sTD, sDD);
        k_cvt<<<gcv, 256, 0, stream>>>(Qf, sDD, QHb + 0, 512, sQH, nullptr, 0, 0);
        // Xm = V Wv + K Wk + Q Wq
        k_mf<false><<<gw, 256, 0, stream>>>(KVb + 256, WvTb, Xmf, 256, 512, 256, 256, 0, 0, 0);
        k_mf<true ><<<gw, 256, 0, stream>>>(KVb + 0,   WkTb, Xmf, 256, 512, 256, 256, 0, 0, 0);
        k_mf<true ><<<gw, 256, 0, stream>>>(QHb + 0,   WqTb, Xmf, 256, 512, 256, 256, 0, 0, 0);
        k_xupd<<<2048, 256, 0, stream>>>(Xf, Xmf, maskf);
    }
    // logits = Xm_rows @ emb^T
    k_gatherb<<<512, 256, 0, stream>>>(Xmf, midx, XRb);
    k_mf<false><<<dim3(4, 250, 1), 256, 0, stream>>>(XRb, embB, out, 256, 256, 256, 32000, 0, 0, 0);
}

// Round 3
// 900.191 us; speedup vs baseline: 3.8987x; 1.5992x over previous
//
#include <hip/hip_runtime.h>
#include <hip/hip_bf16.h>

typedef __attribute__((ext_vector_type(8))) short bf16x8;
typedef __attribute__((ext_vector_type(4))) float f32x4;
typedef unsigned short u16;

static __device__ __forceinline__ u16 f2bf(float f) {
    union { float f; unsigned int i; } c; c.f = f;
    unsigned int r = c.i + 0x7fffu + ((c.i >> 16) & 1u);
    return (u16)(r >> 16);
}

#define AS1(p) ((const __attribute__((address_space(1))) void*)(p))
#define AS3(p) ((__attribute__((address_space(3))) void*)(p))
static __device__ __forceinline__ void glds16(const void* g, void* l) {
    __builtin_amdgcn_global_load_lds(AS1(g), AS3(l), 16, 0, 0);
}

// ---------------- workspace layout (byte offsets) ----------------
static constexpr long B_X    = 0;            // fp32 X   [8,1024,256]   8,388,608
static constexpr long B_XMB  = 8388608;      // fp32 Xm  [8,1024,256]   8,388,608
static constexpr long B_SF   = 16777216;     // fp32 scores [8,1024,1024] 33,554,432 (embB aliases)
static constexpr long B_SXP  = 50331648;     // bf16 [Xp|S]   [8,1024,1280] 20,971,520
static constexpr long B_STXP = 71303168;     // bf16 [Xp|S^T] [8,1024,1280] 20,971,520
static constexpr long B_QH   = 92274688;     // bf16 [Q|H] [8,1024,512] 8,388,608
static constexpr long B_KV   = 100663296;    // bf16 [K|V] [8,1024,512] 8,388,608
static constexpr long B_BQ   = 109051904;    // bf16 [Wq|K^T] [8,256,1280] 5,242,880
static constexpr long B_BK   = 114294784;    // bf16 [Wk|Q^T] [8,256,1280] 5,242,880
static constexpr long B_BV   = 119537664;    // bf16 [Wv|H^T] [8,256,1280] 5,242,880
static constexpr long B_VT   = 124780544;    // bf16 V^T [8,256,1024] 4,194,304
static constexpr long B_WQT  = 128974848;    // bf16 Wq^T [256,256] 131,072
static constexpr long B_WKVT = 129105920;    // bf16 [Wk^T|Wv^T] [256,512] 262,144
static constexpr long B_XRB  = 129368064;    // bf16 gathered rows [512,256] 262,144
static constexpr long B_PE   = 129630208;    // fp32 PE [1024,256] 1,048,576
static constexpr long B_PAD  = 130678784;    // int pad flags
static constexpr long B_MSK  = 130711552;    // int mask flags
// end ~130.7 MB

// ---------------- setup kernels ----------------
__global__ __launch_bounds__(256) void k_pe(float* __restrict__ PE) {
    int g = blockIdx.x * 256 + threadIdx.x;
    int p = g >> 7, j = g & 127;
    float di   = (float)j * (1.0f / 128.0f);
    float freq = powf(10000.0f, -di);
    float ang  = (float)p * freq;
    PE[(long)p * 256 + j]       = sinf(ang);
    PE[(long)p * 256 + j + 128] = cosf(ang);
}

__global__ __launch_bounds__(256) void k_flags(const int* __restrict__ ix,
                                               int* __restrict__ padf, int* __restrict__ maskf) {
    int g = blockIdx.x * 256 + threadIdx.x;
    int t = ix[g];
    padf[g]  = (t == 0) ? 1 : 0;
    maskf[g] = (t == 1) ? 1 : 0;
}

__global__ __launch_bounds__(256) void k_embed(const int* __restrict__ ix,
                                               const float* __restrict__ emb, float* __restrict__ X) {
    int g = blockIdx.x * 256 + threadIdx.x;
    long e = (long)g * 4;
    int bn = (int)(e >> 8), k = (int)(e & 255);
    int tok = ix[bn];
    float4 v;
    if (tok == 1) v = make_float4(0.f, 0.f, 0.f, 0.f);
    else          v = *(const float4*)(emb + (long)tok * 256 + k);
    *(float4*)(X + e) = v;
}

// Xp = bf16(X + PE) -> SXp[...,0:256] and STXp[...,0:256]
__global__ __launch_bounds__(256) void k_xpe(const float* __restrict__ X,
                                             const float* __restrict__ PE,
                                             u16* __restrict__ SXp, u16* __restrict__ STXp) {
    int g = blockIdx.x * 256 + threadIdx.x;
    long e = (long)g * 4;
    long bn = e >> 8;
    int i = (int)(bn & 1023), c = (int)(e & 255);
    float4 x = *(const float4*)(X + e);
    float4 p = *(const float4*)(PE + (long)i * 256 + c);
    ushort4 o;
    o.x = f2bf(x.x + p.x); o.y = f2bf(x.y + p.y);
    o.z = f2bf(x.z + p.z); o.w = f2bf(x.w + p.w);
    long oo = bn * 1280 + c;
    *(ushort4*)(SXp + oo)  = o;
    *(ushort4*)(STXp + oo) = o;
}

// weight [256,256] fp32 -> bf16 replicated into 8 batches (ld 1280) + transpose (bz==0)
__global__ __launch_bounds__(256)
void k_wcvt(const float* __restrict__ W, u16* __restrict__ rep, long repStride,
            u16* __restrict__ T, int ldT) {
    __shared__ u16 tile[32][33];
    const int bx = blockIdx.x, by = blockIdx.y, bz = blockIdx.z;
    const int tx = threadIdx.x & 31, ty = threadIdx.x >> 5;
#pragma unroll
    for (int rr = 0; rr < 32; rr += 8) {
        int r = bx * 32 + ty + rr, c = by * 32 + tx;
        u16 u = f2bf(W[(long)r * 256 + c]);
        rep[(long)bz * repStride + (long)r * 1280 + c] = u;
        if (bz == 0) tile[ty + rr][tx] = u;
    }
    if (bz == 0) {
        __syncthreads();
#pragma unroll
        for (int rr = 0; rr < 32; rr += 8)
            T[(long)(by * 32 + ty + rr) * ldT + bx * 32 + tx] = tile[tx][ty + rr];
    }
}

// emb fp32 -> bf16 elementwise
__global__ __launch_bounds__(256) void k_ecvt(const float* __restrict__ emb, u16* __restrict__ out) {
    int g = blockIdx.x * 256 + threadIdx.x;
    long e = (long)g * 4;
    float4 v = *(const float4*)(emb + e);
    ushort4 o;
    o.x = f2bf(v.x); o.y = f2bf(v.y); o.z = f2bf(v.z); o.w = f2bf(v.w);
    *(ushort4*)(out + e) = o;
}

// ---------------- fused MFMA GEMM, 128x64 tile, bf16-in, bf16-out (row + transposed) ----------------
// C[i,j] = sum_k A[i,k]*B[j,k]; writes outR[i][j] (ld ldR) and outT[j][i] (ld ldT). Pointers pre-offset.
__global__ __launch_bounds__(256)
void k_gbf(const u16* __restrict__ A, int lda, long sA, int K,
           const u16* __restrict__ B, int ldb, long sB,
           u16* __restrict__ outR, int ldR, long sR,
           u16* __restrict__ outT, int ldT, long sT) {
    A    += (long)blockIdx.z * sA;
    B    += (long)blockIdx.z * sB;
    outR += (long)blockIdx.z * sR;
    outT += (long)blockIdx.z * sT;
    const int i0 = blockIdx.x * 128, j0 = blockIdx.y * 64;
    __shared__ u16 As[128 * 32];
    __shared__ u16 Bs[64 * 32];
    __shared__ u16 Tt[64][136];
    const int t = threadIdx.x, w = t >> 6, l = t & 63;
    const int wr = (w >> 1) << 6, wc = (w & 1) << 5;
    const int lr = l & 15, lk = (l >> 4) << 3;
    f32x4 acc[4][2] = {};

    const u16* ga = A + (long)(i0 + (t >> 2)) * lda + ((t & 3) << 3);
    const u16* gb = B + (long)(j0 + (t >> 2)) * ldb + ((t & 3) << 3);
    const long a64 = (long)lda << 6;
    char* lA = (char*)As + (w << 10);
    char* lB = (char*)Bs + (w << 10);

    for (int k0 = 0; k0 < K; k0 += 32) {
        glds16(ga + k0,       lA);
        glds16(ga + k0 + a64, lA + 4096);
        glds16(gb + k0,       lB);
        __syncthreads();
        bf16x8 af[4], bb[2];
#pragma unroll
        for (int m = 0; m < 4; ++m)
            af[m] = *(const bf16x8*)(As + ((wr + (m << 4) + lr) << 5) + lk);
#pragma unroll
        for (int n = 0; n < 2; ++n)
            bb[n] = *(const bf16x8*)(Bs + ((wc + (n << 4) + lr) << 5) + lk);
#pragma unroll
        for (int m = 0; m < 4; ++m)
#pragma unroll
            for (int n = 0; n < 2; ++n)
                acc[m][n] = __builtin_amdgcn_mfma_f32_16x16x32_bf16(af[m], bb[n], acc[m][n], 0, 0, 0);
        __syncthreads();
    }

    // epilogue: direct row-major bf16 stores + LDS-bounce transpose
    const int rb  = wr + ((l >> 4) << 2);
    const int cbl = wc + lr;
#pragma unroll
    for (int m = 0; m < 4; ++m)
#pragma unroll
        for (int n = 0; n < 2; ++n)
#pragma unroll
            for (int j = 0; j < 4; ++j) {
                u16 u = f2bf(acc[m][n][j]);
                int rl = rb + (m << 4) + j;
                int cl = cbl + (n << 4);
                outR[(long)(i0 + rl) * ldR + j0 + cl] = u;
                Tt[cl][rl] = u;
            }
    __syncthreads();
#pragma unroll
    for (int p = 0; p < 4; ++p) {
        int id = p * 256 + t;
        int jj = id >> 4, ch = id & 15;
        uint4 v = *(const uint4*)&Tt[jj][ch << 3];
        *(uint4*)(outT + (long)(j0 + jj) * ldT + i0 + (ch << 3)) = v;
    }
}

// ---------------- MFMA GEMM 128x128, bf16-in, fp32-out (scores) ----------------
__global__ __launch_bounds__(256)
void k_mf(const u16* __restrict__ A, const u16* __restrict__ B, float* __restrict__ C,
          int K, int lda, int ldb, int ldc, long sA, long sB, long sC) {
    A += (long)blockIdx.z * sA;
    B += (long)blockIdx.z * sB;
    C += (long)blockIdx.z * sC;
    const int i0 = blockIdx.x * 128, j0 = blockIdx.y * 128;
    __shared__ u16 As[128 * 32];
    __shared__ u16 Bs[128 * 32];
    const int t = threadIdx.x, w = t >> 6, l = t & 63;
    const int wr = (w >> 1) << 6, wc = (w & 1) << 6;
    const int lr = l & 15, lk = (l >> 4) << 3;
    f32x4 acc[4][4] = {};
    const u16* ga = A + (long)(i0 + (t >> 2)) * lda + ((t & 3) << 3);
    const u16* gb = B + (long)(j0 + (t >> 2)) * ldb + ((t & 3) << 3);
    const long a64 = (long)lda << 6, b64 = (long)ldb << 6;
    char* lA = (char*)As + (w << 10);
    char* lB = (char*)Bs + (w << 10);
    for (int k0 = 0; k0 < K; k0 += 32) {
        glds16(ga + k0,       lA);
        glds16(ga + k0 + a64, lA + 4096);
        glds16(gb + k0,       lB);
        glds16(gb + k0 + b64, lB + 4096);
        __syncthreads();
        bf16x8 af[4], bfr[4];
#pragma unroll
        for (int m = 0; m < 4; ++m)
            af[m] = *(const bf16x8*)(As + ((wr + (m << 4) + lr) << 5) + lk);
#pragma unroll
        for (int n = 0; n < 4; ++n)
            bfr[n] = *(const bf16x8*)(Bs + ((wc + (n << 4) + lr) << 5) + lk);
#pragma unroll
        for (int m = 0; m < 4; ++m)
#pragma unroll
            for (int n = 0; n < 4; ++n)
                acc[m][n] = __builtin_amdgcn_mfma_f32_16x16x32_bf16(af[m], bfr[n], acc[m][n], 0, 0, 0);
        __syncthreads();
    }
    const int rb = i0 + wr + ((l >> 4) << 2);
    const int cb = j0 + wc + lr;
#pragma unroll
    for (int m = 0; m < 4; ++m)
#pragma unroll
        for (int n = 0; n < 4; ++n)
#pragma unroll
            for (int j = 0; j < 4; ++j)
                C[(long)(rb + (m << 4) + j) * ldc + cb + (n << 4)] = acc[m][n][j];
}

// ---------------- MFMA GEMM 128x64, bf16-in, fp32-out (Xm, logits) ----------------
template<bool ACC>
__global__ __launch_bounds__(256)
void k_mff(const u16* __restrict__ A, int lda, int K,
           const u16* __restrict__ B, int ldb,
           float* __restrict__ C, int ldc) {
    const int i0 = blockIdx.x * 128, j0 = blockIdx.y * 64;
    __shared__ u16 As[128 * 32];
    __shared__ u16 Bs[64 * 32];
    const int t = threadIdx.x, w = t >> 6, l = t & 63;
    const int wr = (w >> 1) << 6, wc = (w & 1) << 5;
    const int lr = l & 15, lk = (l >> 4) << 3;
    f32x4 acc[4][2] = {};
    const u16* ga = A + (long)(i0 + (t >> 2)) * lda + ((t & 3) << 3);
    const u16* gb = B + (long)(j0 + (t >> 2)) * ldb + ((t & 3) << 3);
    const long a64 = (long)lda << 6;
    char* lA = (char*)As + (w << 10);
    char* lB = (char*)Bs + (w << 10);
    for (int k0 = 0; k0 < K; k0 += 32) {
        glds16(ga + k0,       lA);
        glds16(ga + k0 + a64, lA + 4096);
        glds16(gb + k0,       lB);
        __syncthreads();
        bf16x8 af[4], bb[2];
#pragma unroll
        for (int m = 0; m < 4; ++m)
            af[m] = *(const bf16x8*)(As + ((wr + (m << 4) + lr) << 5) + lk);
#pragma unroll
        for (int n = 0; n < 2; ++n)
            bb[n] = *(const bf16x8*)(Bs + ((wc + (n << 4) + lr) << 5) + lk);
#pragma unroll
        for (int m = 0; m < 4; ++m)
#pragma unroll
            for (int n = 0; n < 2; ++n)
                acc[m][n] = __builtin_amdgcn_mfma_f32_16x16x32_bf16(af[m], bb[n], acc[m][n], 0, 0, 0);
        __syncthreads();
    }
    const int rb = i0 + wr + ((l >> 4) << 2);
    const int cb = j0 + wc + lr;
#pragma unroll
    for (int m = 0; m < 4; ++m)
#pragma unroll
        for (int n = 0; n < 2; ++n)
#pragma unroll
            for (int j = 0; j < 4; ++j) {
                long off = (long)(rb + (m << 4) + j) * ldc + cb + (n << 4);
                if (ACC) C[off] += acc[m][n][j];
                else     C[off]  = acc[m][n][j];
            }
}

// ---------------- softmax: fp32 scores -> bf16 S rows into SXp[...,256:1280] ----------------
__global__ __launch_bounds__(256)
void k_softmax(const float* __restrict__ Sf, u16* __restrict__ SXp, const int* __restrict__ padf) {
    const int i = blockIdx.x, b = blockIdx.y, t = threadIdx.x;
    const float* row = Sf + ((long)(b * 1024 + i)) * 1024;
    u16* orow = SXp + ((long)(b * 1024 + i)) * 1280 + 256;
    const int* pr = padf + b * 1024;
    const int padi = pr[i];
    float4 v = *(const float4*)(row + t * 4);
    float x[4]; int pm[4];
#pragma unroll
    for (int q = 0; q < 4; ++q) {
        int j = t * 4 + q;
        pm[q] = padi | pr[j];
        x[q] = ((&v.x)[q] + (pm[q] ? -9999.0f : 0.0f)) * 0.0625f;
    }
    float m = fmaxf(fmaxf(x[0], x[1]), fmaxf(x[2], x[3]));
#pragma unroll
    for (int o = 32; o > 0; o >>= 1) m = fmaxf(m, __shfl_down(m, o));
    __shared__ float r1[4], r2[4];
    const int lane = t & 63, wid = t >> 6;
    if (lane == 0) r1[wid] = m;
    __syncthreads();
    m = fmaxf(fmaxf(r1[0], r1[1]), fmaxf(r1[2], r1[3]));
    float e[4]; float s = 0.f;
#pragma unroll
    for (int q = 0; q < 4; ++q) { e[q] = expf(x[q] - m); s += e[q]; }
#pragma unroll
    for (int o = 32; o > 0; o >>= 1) s += __shfl_down(s, o);
    if (lane == 0) r2[wid] = s;
    __syncthreads();
    s = r2[0] + r2[1] + r2[2] + r2[3];
    const float inv = 1.0f / s;
    ushort4 o4;
    o4.x = pm[0] ? (u16)0 : f2bf(e[0] * inv);
    o4.y = pm[1] ? (u16)0 : f2bf(e[1] * inv);
    o4.z = pm[2] ? (u16)0 : f2bf(e[2] * inv);
    o4.w = pm[3] ? (u16)0 : f2bf(e[3] * inv);
    *(ushort4*)(orow + t * 4) = o4;
}

// ---------------- S transpose: SXp[...,256:] -> STXp[...,256:] ----------------
__global__ __launch_bounds__(256)
void k_tr(const u16* __restrict__ src, u16* __restrict__ dst) {
    __shared__ u16 tile[32][33];
    const int bx = blockIdx.x, by = blockIdx.y;
    const long base = (long)blockIdx.z * (1024L * 1280);
    const int tx = threadIdx.x & 31, ty = threadIdx.x >> 5;
#pragma unroll
    for (int r = 0; r < 32; r += 8)
        tile[ty + r][tx] = src[base + (long)(bx * 32 + ty + r) * 1280 + 256 + by * 32 + tx];
    __syncthreads();
#pragma unroll
    for (int r = 0; r < 32; r += 8)
        dst[base + (long)(by * 32 + ty + r) * 1280 + 256 + bx * 32 + tx] = tile[tx][ty + r];
}

// ---------------- X = where(mask, Xm, X) ----------------
__global__ __launch_bounds__(256) void k_xupd(float* __restrict__ X, const float* __restrict__ Xm,
                                              const int* __restrict__ maskf) {
    int g = blockIdx.x * 256 + threadIdx.x;
    long e = (long)g * 4;
    int bn = (int)(e >> 8);
    if (maskf[bn]) *(float4*)(X + e) = *(const float4*)(Xm + e);
}

// ---------------- gather masked Xm rows -> bf16 ----------------
__global__ __launch_bounds__(256) void k_gatherb(const float* __restrict__ Xm,
                                                 const int* __restrict__ midx, u16* __restrict__ R) {
    int r = blockIdx.x, t = threadIdx.x;
    R[(long)r * 256 + t] = f2bf(Xm[(long)midx[r] * 256 + t]);
}

// ---------------- launcher ----------------
extern "C" void kernel_launch(void* const* d_in, const int* in_sizes, int n_in,
                              void* d_out, int out_size, void* d_ws, size_t ws_size,
                              hipStream_t stream) {
    (void)in_sizes; (void)n_in; (void)out_size; (void)ws_size;
    const int*   ix   = (const int*)d_in[0];
    const int*   midx = (const int*)d_in[1];
    const float* emb  = (const float*)d_in[2];
    const float* Wq   = (const float*)d_in[3];
    const float* Wk   = (const float*)d_in[4];
    const float* Wv   = (const float*)d_in[5];

    char* base = (char*)d_ws;
    float* Xf   = (float*)(base + B_X);
    float* Xmf  = (float*)(base + B_XMB);
    float* Sf   = (float*)(base + B_SF);
    u16*   SXp  = (u16*)(base + B_SXP);
    u16*   STXp = (u16*)(base + B_STXP);
    u16*   QHb  = (u16*)(base + B_QH);
    u16*   KVb  = (u16*)(base + B_KV);
    u16*   BQ   = (u16*)(base + B_BQ);
    u16*   BK   = (u16*)(base + B_BK);
    u16*   BV   = (u16*)(base + B_BV);
    u16*   VTb  = (u16*)(base + B_VT);
    u16*   WqTb = (u16*)(base + B_WQT);
    u16*   WKVT = (u16*)(base + B_WKVT);
    u16*   XRb  = (u16*)(base + B_XRB);
    float* PEf  = (float*)(base + B_PE);
    int*   padf  = (int*)(base + B_PAD);
    int*   maskf = (int*)(base + B_MSK);
    u16*   embB = (u16*)(base + B_SF);   // aliases Sf; converted after Sf's last use
    float* out  = (float*)d_out;

    // zero-init S-parts and H-part (required zeros at iter 0)
    hipMemsetAsync(SXp,  0, 20971520, stream);
    hipMemsetAsync(STXp, 0, 20971520, stream);
    hipMemsetAsync(QHb,  0, 8388608,  stream);

    k_pe   <<<512,  256, 0, stream>>>(PEf);
    k_flags<<<32,   256, 0, stream>>>(ix, padf, maskf);
    k_embed<<<2048, 256, 0, stream>>>(ix, emb, Xf);
    const long sB256 = 256L * 1280;
    k_wcvt<<<dim3(8, 8, 8), 256, 0, stream>>>(Wq, BQ, sB256, WqTb,      256);
    k_wcvt<<<dim3(8, 8, 8), 256, 0, stream>>>(Wk, BK, sB256, WKVT,      512);
    k_wcvt<<<dim3(8, 8, 8), 256, 0, stream>>>(Wv, BV, sB256, WKVT + 256, 512);

    const long sSX = 1024L * 1280, sQH = 1024L * 512, sVT = 256L * 1024, sS2 = 1024L * 1024;
    const dim3 gU(8, 4, 8);     // fused updates: 128x64 tiles, 256 blocks
    const dim3 gSc(8, 8, 8);    // scores: 128x128, 512 blocks
    const dim3 gXm(64, 4, 1);   // Xm: M=8192

    for (int it = 0; it < 3; ++it) {
        k_xpe<<<2048, 256, 0, stream>>>(Xf, PEf, SXp, STXp);
        // Q = [Xp|S] @ [Wq|K^T]^T   -> QHb[:,0:256], Q^T -> BK[:,:,256:]
        k_gbf<<<gU, 256, 0, stream>>>(SXp, 1280, sSX, 1280, BQ, 1280, sB256,
                                      QHb, 512, sQH, BK + 256, 1280, sB256);
        // K = [Xp|S^T] @ [Wk|Q^T]^T -> KVb[:,0:256], K^T -> BQ[:,:,256:]
        k_gbf<<<gU, 256, 0, stream>>>(STXp, 1280, sSX, 1280, BK, 1280, sB256,
                                      KVb, 512, sQH, BQ + 256, 1280, sB256);
        // V = [Xp|S^T] @ [Wv|H^T]^T -> KVb[:,256:512], V^T -> VTb
        k_gbf<<<gU, 256, 0, stream>>>(STXp, 1280, sSX, 1280, BV, 1280, sB256,
                                      KVb + 256, 512, sQH, VTb, 1024, sVT);
        // scores = [Q|H] @ [K|V]^T  (fp32)
        k_mf<<<gSc, 256, 0, stream>>>(QHb, KVb, Sf, 512, 512, 512, 1024, sQH, sQH, sS2);
        k_softmax<<<dim3(1024, 8), 256, 0, stream>>>(Sf, SXp, padf);
        k_tr<<<dim3(32, 32, 8), 256, 0, stream>>>(SXp, STXp);
        // H = S @ V  -> QHb[:,256:512], H^T -> BV[:,:,256:]
        k_gbf<<<gU, 256, 0, stream>>>(SXp + 256, 1280, sSX, 1024, VTb, 1024, sVT,
                                      QHb + 256, 512, sQH, BV + 256, 1280, sB256);
        // scores again (new H)
        k_mf<<<gSc, 256, 0, stream>>>(QHb, KVb, Sf, 512, 512, 512, 1024, sQH, sQH, sS2);
        k_softmax<<<dim3(1024, 8), 256, 0, stream>>>(Sf, SXp, padf);
        k_tr<<<dim3(32, 32, 8), 256, 0, stream>>>(SXp, STXp);
        // V, K, Q (second half, same fused forms)
        k_gbf<<<gU, 256, 0, stream>>>(STXp, 1280, sSX, 1280, BV, 1280, sB256,
                                      KVb + 256, 512, sQH, VTb, 1024, sVT);
        k_gbf<<<gU, 256, 0, stream>>>(STXp, 1280, sSX, 1280, BK, 1280, sB256,
                                      KVb, 512, sQH, BQ + 256, 1280, sB256);
        k_gbf<<<gU, 256, 0, stream>>>(SXp, 1280, sSX, 1280, BQ, 1280, sB256,
                                      QHb, 512, sQH, BK + 256, 1280, sB256);
        // Xm = [K|V] @ [Wk^T|Wv^T]^T + Q @ Wq^T'   (fp32)
        k_mff<false><<<gXm, 256, 0, stream>>>(KVb, 512, 512, WKVT, 512, Xmf, 256);
        k_mff<true ><<<gXm, 256, 0, stream>>>(QHb, 512, 256, WqTb, 256, Xmf, 256);
        k_xupd<<<2048, 256, 0, stream>>>(Xf, Xmf, maskf);
    }
    // logits = Xm_rows @ emb^T
    k_gatherb<<<512, 256, 0, stream>>>(Xmf, midx, XRb);
    k_ecvt<<<8000, 256, 0, stream>>>(emb, embB);
    k_mff<false><<<dim3(4, 500, 1), 256, 0, stream>>>(XRb, 256, 256, embB, 256, out, 32000);
}

// Round 4
// 771.488 us; speedup vs baseline: 4.5491x; 1.1668x over previous
//
#include <hip/hip_runtime.h>
#include <hip/hip_bf16.h>

typedef __attribute__((ext_vector_type(8))) short bf16x8;
typedef __attribute__((ext_vector_type(4))) float f32x4;
typedef unsigned short u16;

static __device__ __forceinline__ u16 f2bf(float f) {
    union { float f; unsigned int i; } c; c.f = f;
    unsigned int r = c.i + 0x7fffu + ((c.i >> 16) & 1u);
    return (u16)(r >> 16);
}

#define AS1(p) ((const __attribute__((address_space(1))) void*)(p))
#define AS3(p) ((__attribute__((address_space(3))) void*)(p))
static __device__ __forceinline__ void glds16(const void* g, void* l) {
    __builtin_amdgcn_global_load_lds(AS1(g), AS3(l), 16, 0, 0);
}

// ---------------- workspace layout (byte offsets) ----------------
static constexpr long B_X    = 0;            // fp32 X   [8,1024,256]
static constexpr long B_XMB  = 8388608;      // fp32 Xm  [8,1024,256]
static constexpr long B_SF   = 16777216;     // fp32 scores [8,1024,1024] (embB aliases)
static constexpr long B_SXP  = 50331648;     // bf16 [Xp|S]   [8,1024,1280]
static constexpr long B_STXP = 71303168;     // bf16 [Xp|S^T] [8,1024,1280]
static constexpr long B_QH   = 92274688;     // bf16 [Q|H] [8,1024,512]
static constexpr long B_KV   = 100663296;    // bf16 [K|V] [8,1024,512]
static constexpr long B_BQ   = 109051904;    // bf16 [Wq|K^T] [8,256,1280]
static constexpr long B_BKV  = 114294784;    // bf16 [Wk|Q^T ; Wv|H^T] [8,512,1280]
static constexpr long B_VT   = 124780544;    // bf16 V^T [8,256,1024]
static constexpr long B_WQT  = 128974848;    // bf16 Wq^T [256,256]
static constexpr long B_WKVT = 129105920;    // bf16 [Wk^T|Wv^T] [256,512]
static constexpr long B_XRB  = 129368064;    // bf16 gathered rows [512,256]
static constexpr long B_PE   = 129630208;    // fp32 PE [1024,256]
static constexpr long B_PAD  = 130678784;    // int pad flags
static constexpr long B_MSK  = 130711552;    // int mask flags

// ---------------- setup kernels ----------------
__global__ __launch_bounds__(256) void k_pe(float* __restrict__ PE) {
    int g = blockIdx.x * 256 + threadIdx.x;
    int p = g >> 7, j = g & 127;
    float di   = (float)j * (1.0f / 128.0f);
    float freq = powf(10000.0f, -di);
    float ang  = (float)p * freq;
    PE[(long)p * 256 + j]       = sinf(ang);
    PE[(long)p * 256 + j + 128] = cosf(ang);
}

__global__ __launch_bounds__(256) void k_flags(const int* __restrict__ ix,
                                               int* __restrict__ padf, int* __restrict__ maskf) {
    int g = blockIdx.x * 256 + threadIdx.x;
    int t = ix[g];
    padf[g]  = (t == 0) ? 1 : 0;
    maskf[g] = (t == 1) ? 1 : 0;
}

__global__ __launch_bounds__(256) void k_embed(const int* __restrict__ ix,
                                               const float* __restrict__ emb, float* __restrict__ X) {
    int g = blockIdx.x * 256 + threadIdx.x;
    long e = (long)g * 4;
    int bn = (int)(e >> 8), k = (int)(e & 255);
    int tok = ix[bn];
    float4 v;
    if (tok == 1) v = make_float4(0.f, 0.f, 0.f, 0.f);
    else          v = *(const float4*)(emb + (long)tok * 256 + k);
    *(float4*)(X + e) = v;
}

// Xp = bf16(X + PE) -> SXp[...,0:256] and STXp[...,0:256]
__global__ __launch_bounds__(256) void k_xpe(const float* __restrict__ X,
                                             const float* __restrict__ PE,
                                             u16* __restrict__ SXp, u16* __restrict__ STXp) {
    int g = blockIdx.x * 256 + threadIdx.x;
    long e = (long)g * 4;
    long bn = e >> 8;
    int i = (int)(bn & 1023), c = (int)(e & 255);
    float4 x = *(const float4*)(X + e);
    float4 p = *(const float4*)(PE + (long)i * 256 + c);
    ushort4 o;
    o.x = f2bf(x.x + p.x); o.y = f2bf(x.y + p.y);
    o.z = f2bf(x.z + p.z); o.w = f2bf(x.w + p.w);
    long oo = bn * 1280 + c;
    *(ushort4*)(SXp + oo)  = o;
    *(ushort4*)(STXp + oo) = o;
}

// fused X = where(mask, Xm, X) followed by Xp = bf16(X + PE)
__global__ __launch_bounds__(256) void k_xux(float* __restrict__ X, const float* __restrict__ Xm,
                                             const int* __restrict__ maskf,
                                             const float* __restrict__ PE,
                                             u16* __restrict__ SXp, u16* __restrict__ STXp) {
    int g = blockIdx.x * 256 + threadIdx.x;
    long e = (long)g * 4;
    long bn = e >> 8;
    int i = (int)(bn & 1023), c = (int)(e & 255);
    float4 x = *(const float4*)(X + e);
    if (maskf[bn]) {
        x = *(const float4*)(Xm + e);
        *(float4*)(X + e) = x;
    }
    float4 p = *(const float4*)(PE + (long)i * 256 + c);
    ushort4 o;
    o.x = f2bf(x.x + p.x); o.y = f2bf(x.y + p.y);
    o.z = f2bf(x.z + p.z); o.w = f2bf(x.w + p.w);
    long oo = bn * 1280 + c;
    *(ushort4*)(SXp + oo)  = o;
    *(ushort4*)(STXp + oo) = o;
}

// weight [256,256] fp32 -> bf16 replicated into 8 batches (ld 1280) + transpose (bz==0)
__global__ __launch_bounds__(256)
void k_wcvt(const float* __restrict__ W, u16* __restrict__ rep, long repStride,
            u16* __restrict__ T, int ldT) {
    __shared__ u16 tile[32][33];
    const int bx = blockIdx.x, by = blockIdx.y, bz = blockIdx.z;
    const int tx = threadIdx.x & 31, ty = threadIdx.x >> 5;
#pragma unroll
    for (int rr = 0; rr < 32; rr += 8) {
        int r = bx * 32 + ty + rr, c = by * 32 + tx;
        u16 u = f2bf(W[(long)r * 256 + c]);
        rep[(long)bz * repStride + (long)r * 1280 + c] = u;
        if (bz == 0) tile[ty + rr][tx] = u;
    }
    if (bz == 0) {
        __syncthreads();
#pragma unroll
        for (int rr = 0; rr < 32; rr += 8)
            T[(long)(by * 32 + ty + rr) * ldT + bx * 32 + tx] = tile[tx][ty + rr];
    }
}

// emb fp32 -> bf16 elementwise
__global__ __launch_bounds__(256) void k_ecvt(const float* __restrict__ emb, u16* __restrict__ out) {
    int g = blockIdx.x * 256 + threadIdx.x;
    long e = (long)g * 4;
    float4 v = *(const float4*)(emb + e);
    ushort4 o;
    o.x = f2bf(v.x); o.y = f2bf(v.y); o.z = f2bf(v.z); o.w = f2bf(v.w);
    *(ushort4*)(out + e) = o;
}

// ---------------- fused MFMA GEMM, 128x64 tile, bf16-in, bf16-out (row + dual-dest transposed) ----------------
__global__ __launch_bounds__(256)
void k_gbf(const u16* __restrict__ A, int lda, long sA, int K,
           const u16* __restrict__ B, int ldb, long sB,
           u16* __restrict__ outR, int ldR, long sR,
           u16* __restrict__ outT1, int ldT1, long sT1,
           u16* __restrict__ outT2, int ldT2, long sT2, int jSplit) {
    A    += (long)blockIdx.z * sA;
    B    += (long)blockIdx.z * sB;
    outR += (long)blockIdx.z * sR;
    const int i0 = blockIdx.x * 128, j0 = blockIdx.y * 64;
    u16* T; int ldT; long sT; int jloc;
    if (j0 < jSplit) { T = outT1; ldT = ldT1; sT = sT1; jloc = j0; }
    else             { T = outT2; ldT = ldT2; sT = sT2; jloc = j0 - jSplit; }
    T += (long)blockIdx.z * sT;

    __shared__ u16 As[128 * 32];
    __shared__ u16 Bs[64 * 32];
    __shared__ u16 Tt[64][136];
    const int t = threadIdx.x, w = t >> 6, l = t & 63;
    const int wr = (w >> 1) << 6, wc = (w & 1) << 5;
    const int lr = l & 15, lk = (l >> 4) << 3;
    f32x4 acc[4][2] = {};

    const u16* ga = A + (long)(i0 + (t >> 2)) * lda + ((t & 3) << 3);
    const u16* gb = B + (long)(j0 + (t >> 2)) * ldb + ((t & 3) << 3);
    const long a64 = (long)lda << 6;
    char* lA = (char*)As + (w << 10);
    char* lB = (char*)Bs + (w << 10);

    for (int k0 = 0; k0 < K; k0 += 32) {
        glds16(ga + k0,       lA);
        glds16(ga + k0 + a64, lA + 4096);
        glds16(gb + k0,       lB);
        __syncthreads();
        bf16x8 af[4], bb[2];
#pragma unroll
        for (int m = 0; m < 4; ++m)
            af[m] = *(const bf16x8*)(As + ((wr + (m << 4) + lr) << 5) + lk);
#pragma unroll
        for (int n = 0; n < 2; ++n)
            bb[n] = *(const bf16x8*)(Bs + ((wc + (n << 4) + lr) << 5) + lk);
#pragma unroll
        for (int m = 0; m < 4; ++m)
#pragma unroll
            for (int n = 0; n < 2; ++n)
                acc[m][n] = __builtin_amdgcn_mfma_f32_16x16x32_bf16(af[m], bb[n], acc[m][n], 0, 0, 0);
        __syncthreads();
    }

    const int rb  = wr + ((l >> 4) << 2);
    const int cbl = wc + lr;
#pragma unroll
    for (int m = 0; m < 4; ++m)
#pragma unroll
        for (int n = 0; n < 2; ++n)
#pragma unroll
            for (int j = 0; j < 4; ++j) {
                u16 u = f2bf(acc[m][n][j]);
                int rl = rb + (m << 4) + j;
                int cl = cbl + (n << 4);
                outR[(long)(i0 + rl) * ldR + j0 + cl] = u;
                Tt[cl][rl] = u;
            }
    __syncthreads();
#pragma unroll
    for (int p = 0; p < 4; ++p) {
        int id = p * 256 + t;
        int jj = id >> 4, ch = id & 15;
        uint4 v = *(const uint4*)&Tt[jj][ch << 3];
        *(uint4*)(T + (long)(jloc + jj) * ldT + i0 + (ch << 3)) = v;
    }
}

// ---------------- MFMA GEMM 128x128, bf16-in, fp32-out (scores) ----------------
__global__ __launch_bounds__(256)
void k_mf(const u16* __restrict__ A, const u16* __restrict__ B, float* __restrict__ C,
          int K, int lda, int ldb, int ldc, long sA, long sB, long sC) {
    A += (long)blockIdx.z * sA;
    B += (long)blockIdx.z * sB;
    C += (long)blockIdx.z * sC;
    const int i0 = blockIdx.x * 128, j0 = blockIdx.y * 128;
    __shared__ u16 As[128 * 32];
    __shared__ u16 Bs[128 * 32];
    const int t = threadIdx.x, w = t >> 6, l = t & 63;
    const int wr = (w >> 1) << 6, wc = (w & 1) << 6;
    const int lr = l & 15, lk = (l >> 4) << 3;
    f32x4 acc[4][4] = {};
    const u16* ga = A + (long)(i0 + (t >> 2)) * lda + ((t & 3) << 3);
    const u16* gb = B + (long)(j0 + (t >> 2)) * ldb + ((t & 3) << 3);
    const long a64 = (long)lda << 6, b64 = (long)ldb << 6;
    char* lA = (char*)As + (w << 10);
    char* lB = (char*)Bs + (w << 10);
    for (int k0 = 0; k0 < K; k0 += 32) {
        glds16(ga + k0,       lA);
        glds16(ga + k0 + a64, lA + 4096);
        glds16(gb + k0,       lB);
        glds16(gb + k0 + b64, lB + 4096);
        __syncthreads();
        bf16x8 af[4], bfr[4];
#pragma unroll
        for (int m = 0; m < 4; ++m)
            af[m] = *(const bf16x8*)(As + ((wr + (m << 4) + lr) << 5) + lk);
#pragma unroll
        for (int n = 0; n < 4; ++n)
            bfr[n] = *(const bf16x8*)(Bs + ((wc + (n << 4) + lr) << 5) + lk);
#pragma unroll
        for (int m = 0; m < 4; ++m)
#pragma unroll
            for (int n = 0; n < 4; ++n)
                acc[m][n] = __builtin_amdgcn_mfma_f32_16x16x32_bf16(af[m], bfr[n], acc[m][n], 0, 0, 0);
        __syncthreads();
    }
    const int rb = i0 + wr + ((l >> 4) << 2);
    const int cb = j0 + wc + lr;
#pragma unroll
    for (int m = 0; m < 4; ++m)
#pragma unroll
        for (int n = 0; n < 4; ++n)
#pragma unroll
            for (int j = 0; j < 4; ++j)
                C[(long)(rb + (m << 4) + j) * ldc + cb + (n << 4)] = acc[m][n][j];
}

// ---------------- MFMA GEMM 128x64, bf16-in, fp32-out (Xm, logits) ----------------
template<bool ACC>
__global__ __launch_bounds__(256)
void k_mff(const u16* __restrict__ A, int lda, int K,
           const u16* __restrict__ B, int ldb,
           float* __restrict__ C, int ldc) {
    const int i0 = blockIdx.x * 128, j0 = blockIdx.y * 64;
    __shared__ u16 As[128 * 32];
    __shared__ u16 Bs[64 * 32];
    const int t = threadIdx.x, w = t >> 6, l = t & 63;
    const int wr = (w >> 1) << 6, wc = (w & 1) << 5;
    const int lr = l & 15, lk = (l >> 4) << 3;
    f32x4 acc[4][2] = {};
    const u16* ga = A + (long)(i0 + (t >> 2)) * lda + ((t & 3) << 3);
    const u16* gb = B + (long)(j0 + (t >> 2)) * ldb + ((t & 3) << 3);
    const long a64 = (long)lda << 6;
    char* lA = (char*)As + (w << 10);
    char* lB = (char*)Bs + (w << 10);
    for (int k0 = 0; k0 < K; k0 += 32) {
        glds16(ga + k0,       lA);
        glds16(ga + k0 + a64, lA + 4096);
        glds16(gb + k0,       lB);
        __syncthreads();
        bf16x8 af[4], bb[2];
#pragma unroll
        for (int m = 0; m < 4; ++m)
            af[m] = *(const bf16x8*)(As + ((wr + (m << 4) + lr) << 5) + lk);
#pragma unroll
        for (int n = 0; n < 2; ++n)
            bb[n] = *(const bf16x8*)(Bs + ((wc + (n << 4) + lr) << 5) + lk);
#pragma unroll
        for (int m = 0; m < 4; ++m)
#pragma unroll
            for (int n = 0; n < 2; ++n)
                acc[m][n] = __builtin_amdgcn_mfma_f32_16x16x32_bf16(af[m], bb[n], acc[m][n], 0, 0, 0);
        __syncthreads();
    }
    const int rb = i0 + wr + ((l >> 4) << 2);
    const int cb = j0 + wc + lr;
#pragma unroll
    for (int m = 0; m < 4; ++m)
#pragma unroll
        for (int n = 0; n < 2; ++n)
#pragma unroll
            for (int j = 0; j < 4; ++j) {
                long off = (long)(rb + (m << 4) + j) * ldc + cb + (n << 4);
                if (ACC) C[off] += acc[m][n][j];
                else     C[off]  = acc[m][n][j];
            }
}

// ---------------- fused softmax + S write + S^T write ----------------
// block: 16 rows x 1024 cols. 3 streaming passes over fp32 scores.
__global__ __launch_bounds__(256)
void k_smtr(const float* __restrict__ Sf, u16* __restrict__ SXp, u16* __restrict__ STXp,
            const int* __restrict__ padf) {
    const int bx = blockIdx.x, b = blockIdx.y, t = threadIdx.x;
    const int r = t >> 4, cg = t & 15;
    __shared__ u16   T16[16][1028];     // stride 1028 u16 = 514 words: col reads conflict-free
    __shared__ float padd[1024];
    const int r0 = bx * 16;
    const int row = r0 + r;
    const int* pr = padf + b * 1024;
#pragma unroll
    for (int k = 0; k < 4; ++k)
        padd[t * 4 + k] = pr[t * 4 + k] ? -9999.0f : 0.0f;
    __syncthreads();
    const float prow = pr[row] ? -9999.0f : 0.0f;
    const float* src = Sf + ((long)(b * 1024 + row)) * 1024;

    // pass 1: row max
    float m = -3.0e38f;
#pragma unroll
    for (int q = 0; q < 16; ++q) {
        int c = cg * 4 + q * 64;
        float4 v = *(const float4*)(src + c);
#pragma unroll
        for (int j = 0; j < 4; ++j) {
            float x = ((&v.x)[j] + fminf(prow, padd[c + j])) * 0.0625f;
            m = fmaxf(m, x);
        }
    }
#pragma unroll
    for (int o = 1; o < 16; o <<= 1) m = fmaxf(m, __shfl_xor(m, o));

    // pass 2: row sum
    float s = 0.f;
#pragma unroll
    for (int q = 0; q < 16; ++q) {
        int c = cg * 4 + q * 64;
        float4 v = *(const float4*)(src + c);
#pragma unroll
        for (int j = 0; j < 4; ++j) {
            float x = ((&v.x)[j] + fminf(prow, padd[c + j])) * 0.0625f;
            s += expf(x - m);
        }
    }
#pragma unroll
    for (int o = 1; o < 16; o <<= 1) s += __shfl_xor(s, o);
    const float inv = 1.0f / s;

    // pass 3: write S rows + stage LDS for S^T
    u16* orow = SXp + ((long)(b * 1024 + row)) * 1280 + 256;
#pragma unroll
    for (int q = 0; q < 16; ++q) {
        int c = cg * 4 + q * 64;
        float4 v = *(const float4*)(src + c);
        ushort4 o4;
#pragma unroll
        for (int j = 0; j < 4; ++j) {
            float pmv = fminf(prow, padd[c + j]);
            float x = ((&v.x)[j] + pmv) * 0.0625f;
            float e = expf(x - m) * inv;
            (&o4.x)[j] = (pmv < 0.f) ? (u16)0 : f2bf(e);
        }
        *(ushort4*)(orow + c) = o4;
        *(ushort4*)&T16[r][c] = o4;
    }
    __syncthreads();
    // S^T: 4 cols/thread, 32 B contiguous per col
#pragma unroll
    for (int p = 0; p < 4; ++p) {
        int c = t + p * 256;
        u16 tmp[16];
#pragma unroll
        for (int rr = 0; rr < 16; ++rr) tmp[rr] = T16[rr][c];
        u16* dst = STXp + ((long)(b * 1024 + c)) * 1280 + 256 + r0;
        *(uint4*)(dst)     = *(uint4*)&tmp[0];
        *(uint4*)(dst + 8) = *(uint4*)&tmp[8];
    }
}

// ---------------- gather masked Xm rows -> bf16 ----------------
__global__ __launch_bounds__(256) void k_gatherb(const float* __restrict__ Xm,
                                                 const int* __restrict__ midx, u16* __restrict__ R) {
    int r = blockIdx.x, t = threadIdx.x;
    R[(long)r * 256 + t] = f2bf(Xm[(long)midx[r] * 256 + t]);
}

// ---------------- launcher ----------------
extern "C" void kernel_launch(void* const* d_in, const int* in_sizes, int n_in,
                              void* d_out, int out_size, void* d_ws, size_t ws_size,
                              hipStream_t stream) {
    (void)in_sizes; (void)n_in; (void)out_size; (void)ws_size;
    const int*   ix   = (const int*)d_in[0];
    const int*   midx = (const int*)d_in[1];
    const float* emb  = (const float*)d_in[2];
    const float* Wq   = (const float*)d_in[3];
    const float* Wk   = (const float*)d_in[4];
    const float* Wv   = (const float*)d_in[5];

    char* base = (char*)d_ws;
    float* Xf   = (float*)(base + B_X);
    float* Xmf  = (float*)(base + B_XMB);
    float* Sf   = (float*)(base + B_SF);
    u16*   SXp  = (u16*)(base + B_SXP);
    u16*   STXp = (u16*)(base + B_STXP);
    u16*   QHb  = (u16*)(base + B_QH);
    u16*   KVb  = (u16*)(base + B_KV);
    u16*   BQ   = (u16*)(base + B_BQ);
    u16*   BKV  = (u16*)(base + B_BKV);
    u16*   VTb  = (u16*)(base + B_VT);
    u16*   WqTb = (u16*)(base + B_WQT);
    u16*   WKVT = (u16*)(base + B_WKVT);
    u16*   XRb  = (u16*)(base + B_XRB);
    float* PEf  = (float*)(base + B_PE);
    int*   padf  = (int*)(base + B_PAD);
    int*   maskf = (int*)(base + B_MSK);
    u16*   embB = (u16*)(base + B_SF);   // aliases Sf; converted after Sf's last use
    float* out  = (float*)d_out;

    k_pe   <<<512,  256, 0, stream>>>(PEf);
    k_flags<<<32,   256, 0, stream>>>(ix, padf, maskf);
    k_embed<<<2048, 256, 0, stream>>>(ix, emb, Xf);
    const long sBQ = 256L * 1280, sBKV = 512L * 1280;
    k_wcvt<<<dim3(8, 8, 8), 256, 0, stream>>>(Wq, BQ, sBQ, WqTb, 256);
    k_wcvt<<<dim3(8, 8, 8), 256, 0, stream>>>(Wk, BKV, sBKV, WKVT, 512);
    k_wcvt<<<dim3(8, 8, 8), 256, 0, stream>>>(Wv, BKV + 256L * 1280, sBKV, WKVT + 256, 512);
    k_xpe<<<2048, 256, 0, stream>>>(Xf, PEf, SXp, STXp);

    const long sSX = 1024L * 1280, sQH = 1024L * 512, sVT = 256L * 1024, sS2 = 1024L * 1024;
    const dim3 gQ(8, 4, 8);       // 128x64, N=256
    const dim3 gKV(8, 8, 8);      // 128x64, N=512
    const dim3 gSc(8, 8, 8);      // scores 128x128
    const dim3 gSm(64, 8);        // smtr: 16-row tiles
    const dim3 gXm(64, 4, 1);
    const int  JBIG = 1 << 30;

    for (int it = 0; it < 3; ++it) {
        const int KU = it ? 1280 : 256;      // S parts are zero at iter 0
        if (it) k_xux<<<2048, 256, 0, stream>>>(Xf, Xmf, maskf, PEf, SXp, STXp);
        // Q = [Xp|S][Wq|K^T]^T -> QHb[:,0:256]; Q^T -> BKV rows 0:256, cols 256:
        k_gbf<<<gQ, 256, 0, stream>>>(SXp, 1280, sSX, KU, BQ, 1280, sBQ,
                                      QHb, 512, sQH,
                                      BKV + 256, 1280, sBKV, BKV + 256, 1280, sBKV, JBIG);
        // [K|V] = [Xp|S^T][Wk|Q^T ; Wv|H^T]^T -> KVb; K^T -> BQ cols 256:, V^T -> VTb
        k_gbf<<<gKV, 256, 0, stream>>>(STXp, 1280, sSX, KU, BKV, 1280, sBKV,
                                       KVb, 512, sQH,
                                       BQ + 256, 1280, sBQ, VTb, 1024, sVT, 256);
        // scores = [Q|H][K|V]^T (H=0 at it0 -> K=256)
        k_mf<<<gSc, 256, 0, stream>>>(QHb, KVb, Sf, it ? 512 : 256, 512, 512, 1024, sQH, sQH, sS2);
        k_smtr<<<gSm, 256, 0, stream>>>(Sf, SXp, STXp, padf);
        // H = S V -> QHb[:,256:512]; H^T -> BKV rows 256:512, cols 256:
        k_gbf<<<gQ, 256, 0, stream>>>(SXp + 256, 1280, sSX, 1024, VTb, 1024, sVT,
                                      QHb + 256, 512, sQH,
                                      BKV + 256L * 1280 + 256, 1280, sBKV,
                                      BKV + 256L * 1280 + 256, 1280, sBKV, JBIG);
        // scores again (new H)
        k_mf<<<gSc, 256, 0, stream>>>(QHb, KVb, Sf, 512, 512, 512, 1024, sQH, sQH, sS2);
        k_smtr<<<gSm, 256, 0, stream>>>(Sf, SXp, STXp, padf);
        // [K|V] again (new S^T, new H^T, old Q^T)
        k_gbf<<<gKV, 256, 0, stream>>>(STXp, 1280, sSX, 1280, BKV, 1280, sBKV,
                                       KVb, 512, sQH,
                                       BQ + 256, 1280, sBQ, VTb, 1024, sVT, 256);
        // Q again (new S, new K^T)
        k_gbf<<<gQ, 256, 0, stream>>>(SXp, 1280, sSX, 1280, BQ, 1280, sBQ,
                                      QHb, 512, sQH,
                                      BKV + 256, 1280, sBKV, BKV + 256, 1280, sBKV, JBIG);
        // Xm = [K|V][Wk^T|Wv^T]^T + Q Wq^T'
        k_mff<false><<<gXm, 256, 0, stream>>>(KVb, 512, 512, WKVT, 512, Xmf, 256);
        k_mff<true ><<<gXm, 256, 0, stream>>>(QHb, 512, 256, WqTb, 256, Xmf, 256);
    }
    // logits = Xm_rows @ emb^T
    k_gatherb<<<512, 256, 0, stream>>>(Xmf, midx, XRb);
    k_ecvt<<<8000, 256, 0, stream>>>(emb, embB);
    k_mff<false><<<dim3(4, 500, 1), 256, 0, stream>>>(XRb, 256, 256, embB, 256, out, 32000);
}